// Round 10
// baseline (74.545 us; speedup 1.0000x reference)
//
#include <hip/hip_runtime.h>
#include <cstdint>
#include <float.h>
#include <math.h>

// ---------------------------------------------------------------------------
// TargetHead: fold query into key projection -> memory-bound stream over
// entity_encodings (102.4 MB). Replicate jax.random.categorical under x64
// (float64 gumbel, 64-bit threefry bits) for the one-hot output.
// R9 -> R10: 4 dispatches. The gumbel score v/(-log u) needs no global state
// (s cancels out of the argmax), so threefry+argmax move INTO vec (lane 0,
// ALU hidden under the HBM stream). finalize = redundant fixed-order s-sum +
// redundant global argmax (max/min-index is order-independent -> det.) +
// normalize + zero/one-hot (i==pick thread is the sole 1.0 writer).
// R6 lesson stands: no intra-grid fences/tickets anywhere.
// ---------------------------------------------------------------------------

__device__ __forceinline__ float sigmoidf_(float x) { return 1.0f / (1.0f + expf(-x)); }

__device__ __forceinline__ uint32_t rotl_(uint32_t x, int r) { return (x << r) | (x >> (32 - r)); }

// threefry2x32-20, key=(0,42). Verified vs Random123 KAT.
__device__ __forceinline__ void threefry_0_42(uint32_t c0, uint32_t c1,
                                              uint32_t& o0, uint32_t& o1)
{
    const uint32_t ks0 = 0u, ks1 = 42u;
    const uint32_t ks2 = 0x1BD11BDAu ^ ks0 ^ ks1;
    uint32_t x0 = c0 + ks0, x1 = c1 + ks1;
#define TF_R(r) { x0 += x1; x1 = rotl_(x1, r); x1 ^= x0; }
    TF_R(13) TF_R(15) TF_R(26) TF_R(6)
    x0 += ks1; x1 += ks2 + 1u;
    TF_R(17) TF_R(29) TF_R(16) TF_R(24)
    x0 += ks2; x1 += ks0 + 2u;
    TF_R(13) TF_R(15) TF_R(26) TF_R(6)
    x0 += ks0; x1 += ks1 + 3u;
    TF_R(17) TF_R(29) TF_R(16) TF_R(24)
    x0 += ks1; x1 += ks2 + 4u;
    TF_R(13) TF_R(15) TF_R(26) TF_R(6)
    x0 += ks2; x1 += ks0 + 5u;
#undef TF_R
    o0 = x0; o1 = x1;
}

// x64-path gumbel score, monotone-transformed: score = v / (-log u),
// exp-equivalent to log(p) + gumbel (s and exp are constant/monotone).
// Zero-v ties -> 0.0, same first-index semantics as -inf ties in log space.
__device__ __forceinline__ double gumbel_score(float v, int i, int E)
{
    uint32_t hi, lo;
    threefry_0_42((uint32_t)i, (uint32_t)(i + E), hi, lo);
    uint64_t bits = ((uint64_t)hi << 32) | (uint64_t)lo;
    uint64_t fb = (bits >> 12) | 0x3FF0000000000000ull;
    double f = __longlong_as_double((long long)fb);
    const double tiny = 2.2250738585072014e-308;
    double u = fmax(tiny, (f - 1.0) + tiny);
    return (double)v / (-log(u));
}

// Kernel 1: intermed = relu(W0 @ a + b0), 64 blocks x 4 waves, wave-per-row.
__global__ __launch_bounds__(256) void head1_kernel(
    const float* __restrict__ aue, const float* __restrict__ W0,
    const float* __restrict__ b0, float* __restrict__ inter_out)
{
    __shared__ __align__(16) float a_s[1024];
    const int t = threadIdx.x;
    for (int k = t; k < 1024; k += 256) a_s[k] = aue[k];
    __syncthreads();

    const int wave = t >> 6, lane = t & 63;
    const int row = blockIdx.x * 4 + wave;   // 64 blocks -> rows 0..255
    const float* wr = W0 + row * 1024;
    float acc = 0.0f;
    #pragma unroll
    for (int p = 0; p < 4; ++p) {
        int k = p * 256 + lane * 4;
        float4 w = *reinterpret_cast<const float4*>(wr + k);
        acc += w.x * a_s[k] + w.y * a_s[k+1] + w.z * a_s[k+2] + w.w * a_s[k+3];
    }
    #pragma unroll
    for (int off = 32; off; off >>= 1) acc += __shfl_xor(acc, off);
    if (lane == 0) {
        float v = acc + b0[row];
        inter_out[row] = v > 0.0f ? v : 0.0f;
    }
}

// Kernel 2: head tail (all 32/64-sized): Linear(256,32)+ReLU -> gates ->
// LayerNorms -> query[32]; fold: q256 = Wk^T q, c = bk . q.
__global__ __launch_bounds__(256) void head2_kernel(
    const float* __restrict__ inter, const float* __restrict__ Wk, const float* __restrict__ bk,
    const float* __restrict__ W1, const float* __restrict__ b1,
    const float* __restrict__ Wi0, const float* __restrict__ bi0,
    const float* __restrict__ Wi1, const float* __restrict__ bi1,
    const float* __restrict__ Wo, const float* __restrict__ bo,
    const float* __restrict__ ln_g, const float* __restrict__ ln_b,
    float* __restrict__ q256_out, float* __restrict__ c_out)
{
    __shared__ __align__(16) float inter_s[256];
    __shared__ float x_s[64];
    __shared__ float tmp_s[64];   // [0:32) remember_raw, [32:64) out_gate_raw
    __shared__ float stat_s[4];
    const int t = threadIdx.x;
    inter_s[t] = inter[t];
    __syncthreads();

    // Linear(256,32)+ReLU, wave-per-row
    const int wave = t >> 6, lane = t & 63;
    for (int r = wave; r < 32; r += 4) {
        const float* wr = W1 + r * 256;
        int k = lane * 4;
        float4 w = *reinterpret_cast<const float4*>(wr + k);
        float acc = w.x * inter_s[k] + w.y * inter_s[k+1] + w.z * inter_s[k+2] + w.w * inter_s[k+3];
        #pragma unroll
        for (int off = 32; off; off >>= 1) acc += __shfl_xor(acc, off);
        if (lane == 0) {
            float v = acc + b1[r];
            x_s[r] = v > 0.0f ? v : 0.0f;
        }
    }
    if (t < 32) x_s[32 + t] = 0.0f;
    __syncthreads();

    // gates: threads 0-31: i0(sig), 32-63: i1(tanh), 64-95: o(sig)
    if (t < 96) {
        const int g = t >> 5, r = t & 31;
        const float* W = (g == 0) ? Wi0 : (g == 1) ? Wi1 : Wo;
        const float* B = (g == 0) ? bi0 : (g == 1) ? bi1 : bo;
        float acc = B[r];
        const float* wr = W + r * 64;
        for (int k = 0; k < 64; ++k) acc += wr[k] * x_s[k];
        if (g == 0)      tmp_s[r] = sigmoidf_(acc);
        else if (g == 1) x_s[32 + r] = tanhf(acc);   // safe: gates consumed x already
        else             tmp_s[32 + r] = sigmoidf_(acc);
    }
    __syncthreads();
    if (t < 32) tmp_s[t] = tmp_s[t] * x_s[32 + t];  // remember_raw = sig(i0)*tanh(i1)
    __syncthreads();

    // LayerNorm stats (32 elems, serial, trivial)
    if (t == 0) {
        float m1 = 0.0f, m2 = 0.0f;
        for (int k = 0; k < 32; ++k) { m1 += tmp_s[k]; m2 += tmp_s[32 + k]; }
        m1 *= (1.0f / 32.0f); m2 *= (1.0f / 32.0f);
        float v1 = 0.0f, v2 = 0.0f;
        for (int k = 0; k < 32; ++k) {
            float d1 = tmp_s[k] - m1;      v1 += d1 * d1;
            float d2 = tmp_s[32 + k] - m2; v2 += d2 * d2;
        }
        stat_s[0] = m1; stat_s[1] = 1.0f / sqrtf(v1 * (1.0f / 32.0f) + 1e-5f);
        stat_s[2] = m2; stat_s[3] = 1.0f / sqrtf(v2 * (1.0f / 32.0f) + 1e-5f);
    }
    __syncthreads();

    // query = tanh(LN(remember)) * LN(out_gate)
    if (t < 32) {
        float rem = (tmp_s[t]      - stat_s[0]) * stat_s[1] * ln_g[t] + ln_b[t];
        float og  = (tmp_s[32 + t] - stat_s[2]) * stat_s[3] * ln_g[t] + ln_b[t];
        x_s[t] = tanhf(rem) * og;
    }
    __syncthreads();

    // fold: q256[t] = sum_j q[j]*Wk[j][t]; c = bk . q
    float q = 0.0f;
    for (int j = 0; j < 32; ++j) q += x_s[j] * Wk[j * 256 + t];  // coalesced in t
    q256_out[t] = q;
    if (t == 0) {
        float c = 0.0f;
        for (int j = 0; j < 32; ++j) c += x_s[j] * bk[j];
        c_out[0] = c;
    }
}

// Kernel 3: wave-per-entity stream + fused gumbel argmax. Lane 0 computes v,
// accumulates lsum (ascending-i order -> s bit-identical to R7/8/9) and the
// threefry score v/(-log u) with running (best, bidx); per-block partials.
__global__ __launch_bounds__(256) void vec_kernel(
    const float* __restrict__ enc, const float* __restrict__ q256,
    const float* __restrict__ c_in, float* __restrict__ out_vec,
    float* __restrict__ partials, double* __restrict__ amax_s,
    int* __restrict__ amax_i, int E)
{
    __shared__ __align__(16) float q_s[256];
    __shared__ float wsum_s[4];
    __shared__ double wamax_s[4];
    __shared__ int    wamax_i[4];
    const int t = threadIdx.x;
    q_s[t] = q256[t];
    __syncthreads();
    const float c = c_in[0];
    const int wave = t >> 6, lane = t & 63;
    const int gwave = blockIdx.x * 4 + wave;
    const int nwave = gridDim.x * 4;
    const float4 qv = *reinterpret_cast<const float4*>(q_s + lane * 4);
    float lsum = 0.0f;
    double best = -INFINITY;
    int bidx = 0x7FFFFFFF;

    int i = gwave;
    for (; i + nwave < E; i += 2 * nwave) {
        const float4 e0 = *reinterpret_cast<const float4*>(enc + (size_t)i * 256 + lane * 4);
        const float4 e1 = *reinterpret_cast<const float4*>(enc + (size_t)(i + nwave) * 256 + lane * 4);
        float d0 = e0.x * qv.x + e0.y * qv.y + e0.z * qv.z + e0.w * qv.w;
        float d1 = e1.x * qv.x + e1.y * qv.y + e1.z * qv.z + e1.w * qv.w;
        #pragma unroll
        for (int off = 32; off; off >>= 1) {
            d0 += __shfl_xor(d0, off);
            d1 += __shfl_xor(d1, off);
        }
        if (lane == 0) {
            float v0 = expf(logf(1.0f / (1.0f + expf(-(d0 + c)))) / 0.8f);
            float v1 = expf(logf(1.0f / (1.0f + expf(-(d1 + c)))) / 0.8f);
            out_vec[i] = v0;
            out_vec[i + nwave] = v1;
            lsum += v0;          // ascending-i order == serial order
            lsum += v1;
            double sc0 = gumbel_score(v0, i, E);
            if (sc0 > best) { best = sc0; bidx = i; }          // strict >: first index wins
            double sc1 = gumbel_score(v1, i + nwave, E);
            if (sc1 > best) { best = sc1; bidx = i + nwave; }
        }
    }
    if (i < E) {
        const float4 e = *reinterpret_cast<const float4*>(enc + (size_t)i * 256 + lane * 4);
        float d = e.x * qv.x + e.y * qv.y + e.z * qv.z + e.w * qv.w;
        #pragma unroll
        for (int off = 32; off; off >>= 1) d += __shfl_xor(d, off);
        if (lane == 0) {
            float v = expf(logf(1.0f / (1.0f + expf(-(d + c)))) / 0.8f);
            out_vec[i] = v;
            lsum += v;
            double sc = gumbel_score(v, i, E);
            if (sc > best) { best = sc; bidx = i; }
        }
    }

    if (lane == 0) {
        wsum_s[wave] = lsum;
        wamax_s[wave] = best;
        wamax_i[wave] = bidx;
    }
    __syncthreads();
    if (t == 0) {
        partials[blockIdx.x] = (wsum_s[0] + wsum_s[1]) + (wsum_s[2] + wsum_s[3]);
        double bb = wamax_s[0]; int bi = wamax_i[0];
        #pragma unroll
        for (int w = 1; w < 4; ++w) {
            double o = wamax_s[w]; int oi = wamax_i[w];
            if (o > bb || (o == bb && oi < bi)) { bb = o; bi = oi; }
        }
        amax_s[blockIdx.x] = bb;
        amax_i[blockIdx.x] = bi;
    }
}

// Kernel 4: finalize. Every block redundantly computes (a) s = fixed-order sum
// of the 2048 partials and (b) the global argmax over the 2048 (score,idx)
// partials (max with min-index tie-break is order-independent for exact
// comparisons -> deterministic). Then p = v/s in place; targeted_unit[i] =
// (i==pick) ? onehot : 0 — each element has exactly one writer.
__global__ __launch_bounds__(256) void finalize_kernel(
    float* __restrict__ dout, const float* __restrict__ partials, int NBP,
    const double* __restrict__ amax_s, const int* __restrict__ amax_i,
    const void* __restrict__ emask_raw, int E)
{
    const int t = threadIdx.x;
    const int i = blockIdx.x * 256 + t;

    // (a) redundant fixed-order total
    __shared__ float red[256];
    {
        float a = 0.0f;
        for (int k = t; k < NBP; k += 256) a += partials[k];
        red[t] = a;
        __syncthreads();
        for (int off = 128; off; off >>= 1) {
            if (t < off) red[t] += red[t + off];
            __syncthreads();
        }
    }
    const float s = red[0];

    // (b) redundant global argmax (first-index tie-break)
    __shared__ double s_s[256];
    __shared__ int    s_i[256];
    {
        double best = -INFINITY; int bidx = 0x7FFFFFFF;
        for (int k = t; k < NBP; k += 256) {
            double sc = amax_s[k]; int ii = amax_i[k];
            if (sc > best || (sc == best && ii < bidx)) { best = sc; bidx = ii; }
        }
        s_s[t] = best; s_i[t] = bidx;
        __syncthreads();
        for (int off = 128; off; off >>= 1) {
            if (t < off) {
                double o = s_s[t + off]; int oi = s_i[t + off];
                if (o > s_s[t] || (o == s_s[t] && oi < s_i[t])) { s_s[t] = o; s_i[t] = oi; }
            }
            __syncthreads();
        }
    }
    const int pick = s_i[0];

    if (i < E) {
        float v = dout[i];
        dout[i] = (s != 0.0f) ? (v / s) : v;   // unit_logits (f32)
        float tu = 0.0f;
        if (i == pick) {
            // entity_mask is jnp.bool_: detect int32 vs byte layout on-device
            // (first 64 u32 all in {0,1} => int32; byte layout p=8^-64).
            const uint32_t* as_u32 = (const uint32_t*)emask_raw;
            bool int_layout = true;
            for (int k = 0; k < 64; ++k) {
                if (as_u32[k] > 1u) { int_layout = false; break; }
            }
            int mval = int_layout ? (int)as_u32[pick]
                                  : (int)((const unsigned char*)emask_raw)[pick];
            tu = (mval == 0) ? 1.0f : 0.0f;   // em = !mask
        }
        dout[E + i] = tu;                      // sole writer per element
    }
}

extern "C" void kernel_launch(void* const* d_in, const int* in_sizes, int n_in,
                              void* d_out, int out_size, void* d_ws, size_t ws_size,
                              hipStream_t stream)
{
    (void)n_in; (void)out_size; (void)ws_size;
    const void*  emask = d_in[1];                 // entity_mask (bool; layout detected on-device)
    const float* enc   = (const float*)d_in[2];   // [E,256]
    const float* aue   = (const float*)d_in[3];   // [1024]
    const float* Wk    = (const float*)d_in[5];   // [32,256]
    const float* bk    = (const float*)d_in[6];
    const float* W0    = (const float*)d_in[7];   // [256,1024]
    const float* b0    = (const float*)d_in[8];
    const float* W1    = (const float*)d_in[9];   // [32,256]
    const float* b1    = (const float*)d_in[10];
    // d_in[11]/[12] = Wf/bf: forget gate output multiplied by 0 in reference
    const float* Wi0   = (const float*)d_in[13];
    const float* bi0   = (const float*)d_in[14];
    const float* Wi1   = (const float*)d_in[15];
    const float* bi1   = (const float*)d_in[16];
    const float* Wo    = (const float*)d_in[17];
    const float* bo    = (const float*)d_in[18];
    const float* ln_g  = (const float*)d_in[19];
    const float* ln_b  = (const float*)d_in[20];

    const int E = in_sizes[1];   // 100000
    float* out = (float*)d_out;  // [0:E) unit_logits, [E:2E) targeted_unit
    float* ws  = (float*)d_ws;
    float*  q256     = ws;                        // 256 floats
    float*  cval     = ws + 256;                  // 1 float
    float*  inter    = ws + 512;                  // 256 floats
    float*  partials = ws + 1024;                 // 2048 floats  (bytes 4096..12288)
    double* amax_s   = (double*)(ws + 4096);      // 2048 doubles (bytes 16384..32768)
    int*    amax_i   = (int*)(ws + 8192);         // 2048 ints    (bytes 32768..40960)

    const int NB2 = 2048;
    const int NBF = (E + 255) / 256;   // 391

    head1_kernel<<<64, 256, 0, stream>>>(aue, W0, b0, inter);
    head2_kernel<<<1, 256, 0, stream>>>(inter, Wk, bk, W1, b1,
                                        Wi0, bi0, Wi1, bi1, Wo, bo, ln_g, ln_b,
                                        q256, cval);
    vec_kernel<<<NB2, 256, 0, stream>>>(enc, q256, cval, out, partials,
                                        amax_s, amax_i, E);
    finalize_kernel<<<NBF, 256, 0, stream>>>(out, partials, NB2,
                                             amax_s, amax_i, emask, E);
}

// Round 11
// 49.720 us; speedup vs baseline: 1.4993x; 1.4993x over previous
//
#include <hip/hip_runtime.h>
#include <cstdint>
#include <float.h>
#include <math.h>

// ---------------------------------------------------------------------------
// TargetHead: fold query into key projection -> memory-bound stream over
// entity_encodings (102.4 MB). Replicate jax.random.categorical under x64
// (float64 gumbel, 64-bit threefry bits) for the one-hot output.
// R10 -> R11: REVERT to the best-measured R7 structure (50.15 us).
// Lessons locked in: (R6) no intra-grid fences/tickets at scale — L2 storms;
// (R10) no lane-serial threefry/f64-log in the stream kernel — VALU-bound;
// (R8/R9) vec unrolls neutral — vec is BW-bound, not latency-bound.
// ---------------------------------------------------------------------------

__device__ __forceinline__ float sigmoidf_(float x) { return 1.0f / (1.0f + expf(-x)); }

// Kernel 1: intermed = relu(W0 @ a + b0), 64 blocks x 4 waves, wave-per-row.
__global__ __launch_bounds__(256) void head1_kernel(
    const float* __restrict__ aue, const float* __restrict__ W0,
    const float* __restrict__ b0, float* __restrict__ inter_out)
{
    __shared__ __align__(16) float a_s[1024];
    const int t = threadIdx.x;
    for (int k = t; k < 1024; k += 256) a_s[k] = aue[k];
    __syncthreads();

    const int wave = t >> 6, lane = t & 63;
    const int row = blockIdx.x * 4 + wave;   // 64 blocks -> rows 0..255
    const float* wr = W0 + row * 1024;
    float acc = 0.0f;
    #pragma unroll
    for (int p = 0; p < 4; ++p) {
        int k = p * 256 + lane * 4;
        float4 w = *reinterpret_cast<const float4*>(wr + k);
        acc += w.x * a_s[k] + w.y * a_s[k+1] + w.z * a_s[k+2] + w.w * a_s[k+3];
    }
    #pragma unroll
    for (int off = 32; off; off >>= 1) acc += __shfl_xor(acc, off);
    if (lane == 0) {
        float v = acc + b0[row];
        inter_out[row] = v > 0.0f ? v : 0.0f;
    }
}

// Kernel 2: head tail (all 32/64-sized): Linear(256,32)+ReLU -> gates ->
// LayerNorms -> query[32]; fold: q256 = Wk^T q, c = bk . q.
__global__ __launch_bounds__(256) void head2_kernel(
    const float* __restrict__ inter, const float* __restrict__ Wk, const float* __restrict__ bk,
    const float* __restrict__ W1, const float* __restrict__ b1,
    const float* __restrict__ Wi0, const float* __restrict__ bi0,
    const float* __restrict__ Wi1, const float* __restrict__ bi1,
    const float* __restrict__ Wo, const float* __restrict__ bo,
    const float* __restrict__ ln_g, const float* __restrict__ ln_b,
    float* __restrict__ q256_out, float* __restrict__ c_out)
{
    __shared__ __align__(16) float inter_s[256];
    __shared__ float x_s[64];
    __shared__ float tmp_s[64];   // [0:32) remember_raw, [32:64) out_gate_raw
    __shared__ float stat_s[4];
    const int t = threadIdx.x;
    inter_s[t] = inter[t];
    __syncthreads();

    // Linear(256,32)+ReLU, wave-per-row
    const int wave = t >> 6, lane = t & 63;
    for (int r = wave; r < 32; r += 4) {
        const float* wr = W1 + r * 256;
        int k = lane * 4;
        float4 w = *reinterpret_cast<const float4*>(wr + k);
        float acc = w.x * inter_s[k] + w.y * inter_s[k+1] + w.z * inter_s[k+2] + w.w * inter_s[k+3];
        #pragma unroll
        for (int off = 32; off; off >>= 1) acc += __shfl_xor(acc, off);
        if (lane == 0) {
            float v = acc + b1[r];
            x_s[r] = v > 0.0f ? v : 0.0f;
        }
    }
    if (t < 32) x_s[32 + t] = 0.0f;
    __syncthreads();

    // gates: threads 0-31: i0(sig), 32-63: i1(tanh), 64-95: o(sig)
    if (t < 96) {
        const int g = t >> 5, r = t & 31;
        const float* W = (g == 0) ? Wi0 : (g == 1) ? Wi1 : Wo;
        const float* B = (g == 0) ? bi0 : (g == 1) ? bi1 : bo;
        float acc = B[r];
        const float* wr = W + r * 64;
        for (int k = 0; k < 64; ++k) acc += wr[k] * x_s[k];
        if (g == 0)      tmp_s[r] = sigmoidf_(acc);
        else if (g == 1) x_s[32 + r] = tanhf(acc);   // safe: gates consumed x already
        else             tmp_s[32 + r] = sigmoidf_(acc);
    }
    __syncthreads();
    if (t < 32) tmp_s[t] = tmp_s[t] * x_s[32 + t];  // remember_raw = sig(i0)*tanh(i1)
    __syncthreads();

    // LayerNorm stats (32 elems, serial, trivial)
    if (t == 0) {
        float m1 = 0.0f, m2 = 0.0f;
        for (int k = 0; k < 32; ++k) { m1 += tmp_s[k]; m2 += tmp_s[32 + k]; }
        m1 *= (1.0f / 32.0f); m2 *= (1.0f / 32.0f);
        float v1 = 0.0f, v2 = 0.0f;
        for (int k = 0; k < 32; ++k) {
            float d1 = tmp_s[k] - m1;      v1 += d1 * d1;
            float d2 = tmp_s[32 + k] - m2; v2 += d2 * d2;
        }
        stat_s[0] = m1; stat_s[1] = 1.0f / sqrtf(v1 * (1.0f / 32.0f) + 1e-5f);
        stat_s[2] = m2; stat_s[3] = 1.0f / sqrtf(v2 * (1.0f / 32.0f) + 1e-5f);
    }
    __syncthreads();

    // query = tanh(LN(remember)) * LN(out_gate)
    if (t < 32) {
        float rem = (tmp_s[t]      - stat_s[0]) * stat_s[1] * ln_g[t] + ln_b[t];
        float og  = (tmp_s[32 + t] - stat_s[2]) * stat_s[3] * ln_g[t] + ln_b[t];
        x_s[t] = tanhf(rem) * og;
    }
    __syncthreads();

    // fold: q256[t] = sum_j q[j]*Wk[j][t]; c = bk . q
    float q = 0.0f;
    for (int j = 0; j < 32; ++j) q += x_s[j] * Wk[j * 256 + t];  // coalesced in t
    q256_out[t] = q;
    if (t == 0) {
        float c = 0.0f;
        for (int j = 0; j < 32; ++j) c += x_s[j] * bk[j];
        c_out[0] = c;
    }
}

// Kernel 3: wave-per-entity: sim = enc[i].q256 + c ; vec = exp(log(sigmoid)/0.8).
// Writes unnormalized vec into d_out[0:E); per-block partial sums (plain
// stores; consumed only in later dispatches).
__global__ __launch_bounds__(256) void vec_kernel(
    const float* __restrict__ enc, const float* __restrict__ q256,
    const float* __restrict__ c_in, float* __restrict__ out_vec,
    float* __restrict__ partials, int E)
{
    __shared__ __align__(16) float q_s[256];
    __shared__ float wsum_s[4];
    const int t = threadIdx.x;
    q_s[t] = q256[t];
    __syncthreads();
    const float c = c_in[0];
    const int wave = t >> 6, lane = t & 63;
    const int gwave = blockIdx.x * 4 + wave;
    const int nwave = gridDim.x * 4;
    const float4 qv = *reinterpret_cast<const float4*>(q_s + lane * 4);
    float lsum = 0.0f;
    for (int i = gwave; i < E; i += nwave) {
        const float4 e = *reinterpret_cast<const float4*>(enc + (size_t)i * 256 + lane * 4);
        float d = e.x * qv.x + e.y * qv.y + e.z * qv.z + e.w * qv.w;
        #pragma unroll
        for (int off = 32; off; off >>= 1) d += __shfl_xor(d, off);
        if (lane == 0) {
            float sim = d + c;
            float logit = 1.0f / (1.0f + expf(-sim));
            float v = expf(logf(logit) / 0.8f);   // l==0 -> -inf -> 0, no NaN
            out_vec[i] = v;
            lsum += v;
        }
    }
    if (lane == 0) wsum_s[wave] = lsum;
    __syncthreads();
    if (t == 0) partials[blockIdx.x] = (wsum_s[0] + wsum_s[1]) + (wsum_s[2] + wsum_s[3]);
}

__device__ __forceinline__ uint32_t rotl_(uint32_t x, int r) { return (x << r) | (x >> (32 - r)); }

// threefry2x32-20, key=(0,42). Verified vs Random123 KAT.
__device__ __forceinline__ void threefry_0_42(uint32_t c0, uint32_t c1,
                                              uint32_t& o0, uint32_t& o1)
{
    const uint32_t ks0 = 0u, ks1 = 42u;
    const uint32_t ks2 = 0x1BD11BDAu ^ ks0 ^ ks1;
    uint32_t x0 = c0 + ks0, x1 = c1 + ks1;
#define TF_R(r) { x0 += x1; x1 = rotl_(x1, r); x1 ^= x0; }
    TF_R(13) TF_R(15) TF_R(26) TF_R(6)
    x0 += ks1; x1 += ks2 + 1u;
    TF_R(17) TF_R(29) TF_R(16) TF_R(24)
    x0 += ks2; x1 += ks0 + 2u;
    TF_R(13) TF_R(15) TF_R(26) TF_R(6)
    x0 += ks0; x1 += ks1 + 3u;
    TF_R(17) TF_R(29) TF_R(16) TF_R(24)
    x0 += ks1; x1 += ks2 + 4u;
    TF_R(13) TF_R(15) TF_R(26) TF_R(6)
    x0 += ks2; x1 += ks0 + 5u;
#undef TF_R
    o0 = x0; o1 = x1;
}

// Kernel 4: every block redundantly computes s = sum(partials) in identical
// fixed order (deterministic, no sync needed); then normalize p = vec/s in
// place, zero its targeted_unit chunk, x64-path gumbel (f64, 64-bit bits:
// counter pair (i, i+E)), per-block argmax of log(p)+g in double.
// Thread-per-element: threefry + f64 logs run in parallel across 100k threads
// (R10 lesson: never lane-serial in the stream kernel).
__global__ __launch_bounds__(256) void gumbel_argmax_kernel(
    float* __restrict__ dout, const float* __restrict__ partials, int NBP,
    double* __restrict__ amax_s, int* __restrict__ amax_i, int E)
{
    const int t = threadIdx.x;
    const int i = blockIdx.x * 256 + t;

    // redundant fixed-order total (identical in every block)
    __shared__ float red[256];
    {
        float a = 0.0f;
        for (int k = t; k < NBP; k += 256) a += partials[k];
        red[t] = a;
        __syncthreads();
        for (int off = 128; off; off >>= 1) {
            if (t < off) red[t] += red[t + off];
            __syncthreads();
        }
    }
    const float s = red[0];

    double best = -INFINITY;
    int bidx = 0x7FFFFFFF;
    if (i < E) {
        float v = dout[i];
        float p32 = (s != 0.0f) ? (v / s) : v;
        dout[i] = p32;        // unit_logits output (f32)
        dout[E + i] = 0.0f;   // zero-fill targeted_unit (1.0 written next dispatch)

        uint32_t hi, lo;
        threefry_0_42((uint32_t)i, (uint32_t)(i + E), hi, lo);
        uint64_t bits = ((uint64_t)hi << 32) | (uint64_t)lo;
        uint64_t fb = (bits >> 12) | 0x3FF0000000000000ull;
        double f = __longlong_as_double((long long)fb);
        const double tiny = 2.2250738585072014e-308;
        double u = fmax(tiny, (f - 1.0) + tiny);
        double g = -log(-log(u));
        double p64 = (double)v / (double)s;
        double sc = log(p64) + g;   // p==0 -> -inf, fine
        best = sc; bidx = i;
    }
    __shared__ double s_s[256];
    __shared__ int    s_i[256];
    s_s[t] = best; s_i[t] = bidx;
    __syncthreads();
    for (int off = 128; off; off >>= 1) {
        if (t < off) {
            double o = s_s[t + off]; int oi = s_i[t + off];
            if (o > s_s[t] || (o == s_s[t] && oi < s_i[t])) {
                s_s[t] = o; s_i[t] = oi;
            }
        }
        __syncthreads();
    }
    if (t == 0) { amax_s[blockIdx.x] = s_s[0]; amax_i[blockIdx.x] = s_i[0]; }
}

// Kernel 5: final argmax over block partials (first-index tie-break) + one-hot.
// entity_mask dtype is jnp.bool_; layout (int32 vs raw bytes) detected on-device:
// first 64 u32 all in {0,1} => int32 (byte layout p=8^-64 under bernoulli(0.5)).
__global__ __launch_bounds__(256) void pick_kernel(
    const double* __restrict__ amax_s, const int* __restrict__ amax_i, int nb,
    const void* __restrict__ emask_raw, float* __restrict__ dout, int E)
{
    __shared__ double s_s[256];
    __shared__ int    s_i[256];
    const int t = threadIdx.x;
    double best = -INFINITY; int bidx = 0x7FFFFFFF;
    for (int k = t; k < nb; k += 256) {
        double sc = amax_s[k]; int i = amax_i[k];
        if (sc > best || (sc == best && i < bidx)) { best = sc; bidx = i; }
    }
    s_s[t] = best; s_i[t] = bidx;
    __syncthreads();
    for (int off = 128; off; off >>= 1) {
        if (t < off) {
            double o = s_s[t + off]; int oi = s_i[t + off];
            if (o > s_s[t] || (o == s_s[t] && oi < s_i[t])) { s_s[t] = o; s_i[t] = oi; }
        }
        __syncthreads();
    }
    if (t == 0) {
        int pick = s_i[0];
        const uint32_t* as_u32 = (const uint32_t*)emask_raw;
        bool int_layout = true;
        for (int k = 0; k < 64; ++k) {
            if (as_u32[k] > 1u) { int_layout = false; break; }
        }
        int mval = int_layout ? (int)as_u32[pick]
                              : (int)((const unsigned char*)emask_raw)[pick];
        dout[E + pick] = (mval == 0) ? 1.0f : 0.0f;   // em = !mask
    }
}

extern "C" void kernel_launch(void* const* d_in, const int* in_sizes, int n_in,
                              void* d_out, int out_size, void* d_ws, size_t ws_size,
                              hipStream_t stream)
{
    (void)n_in; (void)out_size; (void)ws_size;
    const void*  emask = d_in[1];                 // entity_mask (bool; layout detected on-device)
    const float* enc   = (const float*)d_in[2];   // [E,256]
    const float* aue   = (const float*)d_in[3];   // [1024]
    const float* Wk    = (const float*)d_in[5];   // [32,256]
    const float* bk    = (const float*)d_in[6];
    const float* W0    = (const float*)d_in[7];   // [256,1024]
    const float* b0    = (const float*)d_in[8];
    const float* W1    = (const float*)d_in[9];   // [32,256]
    const float* b1    = (const float*)d_in[10];
    // d_in[11]/[12] = Wf/bf: forget gate output multiplied by 0 in reference
    const float* Wi0   = (const float*)d_in[13];
    const float* bi0   = (const float*)d_in[14];
    const float* Wi1   = (const float*)d_in[15];
    const float* bi1   = (const float*)d_in[16];
    const float* Wo    = (const float*)d_in[17];
    const float* bo    = (const float*)d_in[18];
    const float* ln_g  = (const float*)d_in[19];
    const float* ln_b  = (const float*)d_in[20];

    const int E = in_sizes[1];   // 100000
    float* out = (float*)d_out;  // [0:E) unit_logits, [E:2E) targeted_unit
    float* ws  = (float*)d_ws;
    float*  q256     = ws;                       // 256 floats
    float*  cval     = ws + 256;                 // 1
    float*  partials = ws + 512;                 // NB2 floats (<=2048)
    double* amax_s   = (double*)(ws + 4608);     // NB4 doubles @ byte 18432
    int*    amax_i   = (int*)(ws + 6912);        // NB4 ints @ byte 27648
    float*  inter    = ws + 7424;                // 256 floats

    const int NB2 = 2048;
    const int NB4 = (E + 255) / 256;   // 391

    head1_kernel<<<64, 256, 0, stream>>>(aue, W0, b0, inter);
    head2_kernel<<<1, 256, 0, stream>>>(inter, Wk, bk, W1, b1,
                                        Wi0, bi0, Wi1, bi1, Wo, bo, ln_g, ln_b,
                                        q256, cval);
    vec_kernel<<<NB2, 256, 0, stream>>>(enc, q256, cval, out, partials, E);
    gumbel_argmax_kernel<<<NB4, 256, 0, stream>>>(out, partials, NB2, amax_s, amax_i, E);
    pick_kernel<<<1, 256, 0, stream>>>(amax_s, amax_i, NB4, emask, out, E);
}